// Round 14
// baseline (100.142 us; speedup 1.0000x reference)
//
#include <hip/hip_runtime.h>
#include <stdint.h>

// ---------------------------------------------------------------------------
// Fused MHA v14 (= proven v13 + double-buffered proj):
//   convert_w -> proj (64-row blocks, dbuf 1-barrier/chunk; V stored
//   pi-permuted V^T) -> flash attn (v13-proven: 256-thr/4-wave, 32 q/wave,
//   128-key phases, explicit dbuf, swapped QK^T, static-max exp2, ones-MFMA
//   row-sums, split-K=8, bf16 partials, XCD swizzle, perm P pack,
//   __launch_bounds__(256,4) -> VGPR 60) ->
//   oproj (fused combine+normalize+bias, col-split)
// v_cvt_pk_bf16_f32 BANNED (v8/v10: absmax 3.051758e-3 from P pack alone).
// MFMA v_mfma_f32_16x16x32_bf16 layouts (HW-verified r1/r3):
//   A: row=lane&15, k=8*(lane>>4)+j ; B: col=lane&15, k=8*(lane>>4)+j
//   D: col=lane&15, row=4*(lane>>4)+reg
// P residence after swapped QK^T: lane(g,c) holds P[key][q=c]; as B-operand
// k=8g+j maps to key pi(8g+j) (pi: key bits = k2 k4 k3 k1 k0). V^T is stored
// to global with key-slot sigma(t) = (t&~31) | pi^-1(t&31) so contiguous
// A-fragment reads deliver V[pi(k)][vd] directly.  [proven v3..v6,v11,v13]
// ---------------------------------------------------------------------------

typedef float f32x4 __attribute__((ext_vector_type(4)));
typedef __bf16 bf16x8 __attribute__((ext_vector_type(8)));

extern "C" __device__ float __ocml_native_exp2_f32(float);

__device__ __forceinline__ unsigned short f2bf(float f) {
  unsigned int u = __builtin_bit_cast(unsigned int, f);
  u += 0x7FFFu + ((u >> 16) & 1u);          // RNE
  return (unsigned short)(u >> 16);
}
__device__ __forceinline__ float bf2f(unsigned u) {
  return __builtin_bit_cast(float, u << 16);
}
__device__ __forceinline__ f32x4 mfma16(bf16x8 a, bf16x8 b, f32x4 c) {
  return __builtin_amdgcn_mfma_f32_16x16x32_bf16(a, b, c, 0, 0, 0);
}
__device__ __forceinline__ float ex2(float x) {
#if __has_builtin(__builtin_amdgcn_exp2f)
  return __builtin_amdgcn_exp2f(x);
#else
  return __ocml_native_exp2_f32(x);
#endif
}
// software RNE pair-pack (PROVEN; weights, staging, partials, combine)
__device__ __forceinline__ unsigned pk2(float a, float b) {
  unsigned short ua = __builtin_bit_cast(unsigned short, (__bf16)a);
  unsigned short ub = __builtin_bit_cast(unsigned short, (__bf16)b);
  return (unsigned)ua | ((unsigned)ub << 16);
}
// fast round-half-up pair-pack — IN-LOOP P PACK ONLY (proven v11, 4.88e-4)
__device__ __forceinline__ unsigned pk2p(float a, float b) {
  unsigned au = __builtin_bit_cast(unsigned, a) + 0x8000u;
  unsigned bu = __builtin_bit_cast(unsigned, b) + 0x8000u;
#if __has_builtin(__builtin_amdgcn_perm)
  return __builtin_amdgcn_perm(bu, au, 0x07060302u);
#else
  return (au >> 16) | (bu & 0xffff0000u);
#endif
}
__device__ __forceinline__ uint2 pack4(f32x4 a) {
  uint2 r;
  r.x = pk2(a[0], a[1]);
  r.y = pk2(a[2], a[3]);
  return r;
}

#define QSCALE 0.25503483f  /* log2(e)/sqrt(32) */

// ---------------------------------------------------------------------------
// Convert weights f32 [256k][256n] -> bf16 transposed [256n][256k].
// ---------------------------------------------------------------------------
__global__ __launch_bounds__(256) void convert_w_kernel(
    const float* __restrict__ wq, const float* __restrict__ wk,
    const float* __restrict__ wv, const float* __restrict__ wo,
    unsigned short* __restrict__ tq, unsigned short* __restrict__ tk,
    unsigned short* __restrict__ tv, unsigned short* __restrict__ to)
{
  const int mat = blockIdx.x >> 6, k0 = (blockIdx.x & 63) * 4, n = threadIdx.x;
  const float* src; unsigned short* dst;
  if (mat == 0) { src = wq; dst = tq; }
  else if (mat == 1) { src = wk; dst = tk; }
  else if (mat == 2) { src = wv; dst = tv; }
  else { src = wo; dst = to; }
  float e0 = src[(size_t)(k0 + 0) * 256 + n];
  float e1 = src[(size_t)(k0 + 1) * 256 + n];
  float e2 = src[(size_t)(k0 + 2) * 256 + n];
  float e3 = src[(size_t)(k0 + 3) * 256 + n];
  uint2 pk = { pk2(e0, e1), pk2(e2, e3) };
  *(uint2*)&dst[(size_t)n * 256 + k0] = pk;
}

// ---------------------------------------------------------------------------
// All three projections, double-buffered (attn's proven 2-per-iter pattern).
// 512 thr = 8 waves; 64 rows x 256 cols. blockIdx.y: 0=Q, 1=K, 2=V (pi-perm).
// LDS: 2 x (64x40 + 256x40) x 2B = 51.2 KB -> 3 blocks/CU at 768-block grid.
// ---------------------------------------------------------------------------
__global__ __launch_bounds__(512) void proj6_kernel(
    const float* __restrict__ Xq, const float* __restrict__ Xk,
    const float* __restrict__ Xv,
    const unsigned short* __restrict__ Wtq, const unsigned short* __restrict__ Wtk,
    const unsigned short* __restrict__ Wtv,
    const float* __restrict__ Bq, const float* __restrict__ Bk,
    const float* __restrict__ Bv,
    unsigned short* __restrict__ Oq, unsigned short* __restrict__ Ok,
    unsigned short* __restrict__ Ov)
{
  const int mat = blockIdx.y;
  const float* X; const unsigned short* Wt; const float* Bp; unsigned short* Op;
  int N; float scale; int vmode;
  if (mat == 0) {
    if (blockIdx.x >= 32) return;
    X = Xq; Wt = Wtq; Bp = Bq; Op = Oq; N = 2048; scale = QSCALE; vmode = 0;
  } else if (mat == 1) {
    X = Xk; Wt = Wtk; Bp = Bk; Op = Ok; N = 16384; scale = 1.f; vmode = 0;
  } else {
    X = Xv; Wt = Wtv; Bp = Bv; Op = Ov; N = 16384; scale = 1.f; vmode = 1;
  }
  const int tid = threadIdx.x;
  const int w = tid >> 6, lane = tid & 63, g = lane >> 4, c = lane & 15;
  const int m0 = blockIdx.x * 64;

  __shared__ __align__(16) unsigned short Xs0[64 * 40], Xs1[64 * 40];
  __shared__ __align__(16) unsigned short Ws0[256 * 40], Ws1[256 * 40];

  const f32x4 zero4 = {0.f, 0.f, 0.f, 0.f};
  f32x4 acc[4][2];
  #pragma unroll
  for (int i = 0; i < 4; ++i) { acc[i][0] = zero4; acc[i][1] = zero4; }

  const int xrow = tid >> 3, xseg = (tid & 7) * 4;   // 64x32 f32 -> 1 float4/thr
  const int wrow = tid >> 1, wseg = (tid & 1) * 16;  // 256x32 bf16 -> 2 int4/thr
  const float* xp0 = &X[(size_t)(m0 + xrow) * 256 + xseg];
  const unsigned short* wp0 = Wt + (size_t)wrow * 256 + wseg;

  auto compute = [&](const unsigned short* Xb, const unsigned short* Wb) {
    bf16x8 a[4], b[2];
    #pragma unroll
    for (int rt = 0; rt < 4; ++rt)
      a[rt] = *(const bf16x8*)&Xb[(16 * rt + c) * 40 + 8 * g];
    #pragma unroll
    for (int ct = 0; ct < 2; ++ct)
      b[ct] = *(const bf16x8*)&Wb[(32 * w + 16 * ct + c) * 40 + 8 * g];
    #pragma unroll
    for (int rt = 0; rt < 4; ++rt)
      #pragma unroll
      for (int ct = 0; ct < 2; ++ct)
        acc[rt][ct] = mfma16(a[rt], b[ct], acc[rt][ct]);
  };

  // prologue: stage chunk 0 -> buf0 directly; prefetch chunk 1 into regs
  {
    float4 x = *(const float4*)xp0;
    *(uint2*)&Xs0[xrow * 40 + xseg] = uint2{ pk2(x.x, x.y), pk2(x.z, x.w) };
    int4 w0 = *(const int4*)wp0;
    int4 w1 = *(const int4*)(wp0 + 8);
    *(int4*)&Ws0[wrow * 40 + wseg] = w0;
    *(int4*)&Ws0[wrow * 40 + wseg + 8] = w1;
  }
  float4 xr = *(const float4*)(xp0 + 32);
  int4 wr0 = *(const int4*)(wp0 + 32);
  int4 wr1 = *(const int4*)(wp0 + 40);
  __syncthreads();

  for (int i = 0; i < 4; ++i) {
    // ---- chunk 2i on buf0; write chunk 2i+1 -> buf1; prefetch 2i+2 ----
    *(uint2*)&Xs1[xrow * 40 + xseg] = uint2{ pk2(xr.x, xr.y), pk2(xr.z, xr.w) };
    *(int4*)&Ws1[wrow * 40 + wseg] = wr0;
    *(int4*)&Ws1[wrow * 40 + wseg + 8] = wr1;
    {
      const int t = (2 * i + 2) & 7;                 // last -> dummy chunk 0
      xr = *(const float4*)(xp0 + t * 32);
      wr0 = *(const int4*)(wp0 + t * 32);
      wr1 = *(const int4*)(wp0 + t * 32 + 8);
    }
    compute(Xs0, Ws0);
    __syncthreads();
    // ---- chunk 2i+1 on buf1; write chunk 2i+2 -> buf0; prefetch 2i+3 ----
    *(uint2*)&Xs0[xrow * 40 + xseg] = uint2{ pk2(xr.x, xr.y), pk2(xr.z, xr.w) };
    *(int4*)&Ws0[wrow * 40 + wseg] = wr0;
    *(int4*)&Ws0[wrow * 40 + wseg + 8] = wr1;
    {
      const int t = (2 * i + 3) & 7;
      xr = *(const float4*)(xp0 + t * 32);
      wr0 = *(const int4*)(wp0 + t * 32);
      wr1 = *(const int4*)(wp0 + t * 32 + 8);
    }
    compute(Xs1, Ws1);
    __syncthreads();
  }

  #pragma unroll
  for (int ct = 0; ct < 2; ++ct) {
    const int col = 32 * w + 16 * ct + c;
    const float bv = Bp[col];
    const int hh = col >> 5, d = col & 31;
    #pragma unroll
    for (int rt = 0; rt < 4; ++rt)
      #pragma unroll
      for (int r = 0; r < 4; ++r) {
        const int row = m0 + 16 * rt + 4 * g + r;
        const unsigned short v = f2bf((acc[rt][ct][r] + bv) * scale);
        if (vmode) {
          const int pr = (row & ~31) | (((row >> 3) & 1) << 4) |
                         (((row >> 2) & 1) << 3) | (((row >> 4) & 1) << 2) |
                         (row & 3);
          Op[((size_t)hh * 32 + d) * (size_t)N + pr] = v;
        } else {
          Op[((size_t)hh * N + row) * 32 + d] = v;
        }
      }
  }
}

// ---------------------------------------------------------------------------
// Flash attention v14 (= proven v13, unchanged).
// ---------------------------------------------------------------------------
__global__ __launch_bounds__(256, 4) void attn14_kernel(
    const unsigned short* __restrict__ qh, const unsigned short* __restrict__ kh,
    const unsigned short* __restrict__ vth,
    unsigned short* __restrict__ part_o, float* __restrict__ part_l)
{
  const int f = blockIdx.x + 16 * (blockIdx.y + 8 * blockIdx.z);
  const int v = (f & 7) * 128 + (f >> 3);
  const int qb = v & 15, h = (v >> 4) & 7, sp = v >> 7;

  const int tid = threadIdx.x;
  const int w = tid >> 6, lane = tid & 63, g = lane >> 4, c = lane & 15;
  const int q0 = qb * 128 + w * 32;

  __shared__ __align__(16) unsigned short K0a[64 * 40], K0b[64 * 40];
  __shared__ __align__(16) unsigned short K1a[64 * 40], K1b[64 * 40];
  __shared__ __align__(16) unsigned short V0a[32 * 72], V0b[32 * 72];
  __shared__ __align__(16) unsigned short V1a[32 * 72], V1b[32 * 72];

  const bf16x8 qf0 = *(const bf16x8*)&qh[((size_t)h * 2048 + q0 + c) * 32 + 8 * g];
  const bf16x8 qf1 = *(const bf16x8*)&qh[((size_t)h * 2048 + q0 + 16 + c) * 32 + 8 * g];

  bf16x8 ones;
  #pragma unroll
  for (int j = 0; j < 8; ++j) ones[j] = (__bf16)1.0f;

  const f32x4 zero4 = {0.f, 0.f, 0.f, 0.f};
  f32x4 acc00 = zero4, acc01 = zero4, acc10 = zero4, acc11 = zero4;
  f32x4 accL0 = zero4, accL1 = zero4;

  const int skey = tid >> 2, sseg = (tid & 3) * 8;
  const int kwoff = skey * 40 + sseg;
  const int vrow = tid >> 3, vseg = (tid & 7) * 8;
  const int vwoff = vrow * 72 + vseg;

  const unsigned short* kp = kh + (size_t)h * 524288 +
                             ((size_t)(sp * 2048) + skey) * 32 + sseg;
  const unsigned short* vp = vth + ((size_t)h * 32 + vrow) * 16384 +
                             sp * 2048 + vseg;

  auto compute = [&](const unsigned short* Kb, const unsigned short* Vb) {
    bf16x8 kf0 = *(const bf16x8*)&Kb[(c) * 40 + 8 * g];
    bf16x8 kf1 = *(const bf16x8*)&Kb[(16 + c) * 40 + 8 * g];
    bf16x8 kf2 = *(const bf16x8*)&Kb[(32 + c) * 40 + 8 * g];
    bf16x8 kf3 = *(const bf16x8*)&Kb[(48 + c) * 40 + 8 * g];
    f32x4 s0 = mfma16(kf0, qf0, zero4);
    f32x4 s1 = mfma16(kf1, qf0, zero4);
    f32x4 s2 = mfma16(kf2, qf0, zero4);
    f32x4 s3 = mfma16(kf3, qf0, zero4);
    f32x4 t0 = mfma16(kf0, qf1, zero4);
    f32x4 t1 = mfma16(kf1, qf1, zero4);
    f32x4 t2 = mfma16(kf2, qf1, zero4);
    f32x4 t3 = mfma16(kf3, qf1, zero4);

    union { unsigned u[4]; bf16x8 v; } pa00, pa01, pa10, pa11;
    pa00.u[0] = pk2p(ex2(s0[0]), ex2(s0[1]));
    pa00.u[1] = pk2p(ex2(s0[2]), ex2(s0[3]));
    pa00.u[2] = pk2p(ex2(s1[0]), ex2(s1[1]));
    pa00.u[3] = pk2p(ex2(s1[2]), ex2(s1[3]));
    pa01.u[0] = pk2p(ex2(s2[0]), ex2(s2[1]));
    pa01.u[1] = pk2p(ex2(s2[2]), ex2(s2[3]));
    pa01.u[2] = pk2p(ex2(s3[0]), ex2(s3[1]));
    pa01.u[3] = pk2p(ex2(s3[2]), ex2(s3[3]));
    pa10.u[0] = pk2p(ex2(t0[0]), ex2(t0[1]));
    pa10.u[1] = pk2p(ex2(t0[2]), ex2(t0[3]));
    pa10.u[2] = pk2p(ex2(t1[0]), ex2(t1[1]));
    pa10.u[3] = pk2p(ex2(t1[2]), ex2(t1[3]));
    pa11.u[0] = pk2p(ex2(t2[0]), ex2(t2[1]));
    pa11.u[1] = pk2p(ex2(t2[2]), ex2(t2[3]));
    pa11.u[2] = pk2p(ex2(t3[0]), ex2(t3[1]));
    pa11.u[3] = pk2p(ex2(t3[2]), ex2(t3[3]));

    bf16x8 v00 = *(const bf16x8*)&Vb[c * 72 + 8 * g];
    bf16x8 v01 = *(const bf16x8*)&Vb[c * 72 + 32 + 8 * g];
    bf16x8 v10 = *(const bf16x8*)&Vb[(16 + c) * 72 + 8 * g];
    bf16x8 v11 = *(const bf16x8*)&Vb[(16 + c) * 72 + 32 + 8 * g];
    __builtin_amdgcn_s_setprio(1);
    acc00 = mfma16(v00, pa00.v, acc00);
    acc01 = mfma16(v10, pa00.v, acc01);
    accL0 = mfma16(ones, pa00.v, accL0);
    acc00 = mfma16(v01, pa01.v, acc00);
    acc01 = mfma16(v11, pa01.v, acc01);
    accL0 = mfma16(ones, pa01.v, accL0);
    acc10 = mfma16(v00, pa10.v, acc10);
    acc11 = mfma16(v10, pa10.v, acc11);
    accL1 = mfma16(ones, pa10.v, accL1);
    acc10 = mfma16(v01, pa11.v, acc10);
    acc11 = mfma16(v11, pa11.v, acc11);
    accL1 = mfma16(ones, pa11.v, accL1);
    __builtin_amdgcn_s_setprio(0);
  };

  {
    int4 ka = *(const int4*)kp;
    int4 va = *(const int4*)vp;
    int4 kb = *(const int4*)(kp + 2048);
    int4 vb = *(const int4*)(vp + 64);
    *(int4*)&K0a[kwoff] = ka;
    *(int4*)&V0a[vwoff] = va;
    *(int4*)&K0b[kwoff] = kb;
    *(int4*)&V0b[vwoff] = vb;
  }
  int4 kr0 = *(const int4*)(kp + 2 * 2048);
  int4 vr0 = *(const int4*)(vp + 2 * 64);
  int4 kr1 = *(const int4*)(kp + 3 * 2048);
  int4 vr1 = *(const int4*)(vp + 3 * 64);
  __syncthreads();

  for (int i = 0; i < 8; ++i) {
    *(int4*)&K1a[kwoff] = kr0;
    *(int4*)&V1a[vwoff] = vr0;
    *(int4*)&K1b[kwoff] = kr1;
    *(int4*)&V1b[vwoff] = vr1;
    {
      const int ta = (4 * i + 4) & 31, tb = (4 * i + 5) & 31;
      kr0 = *(const int4*)(kp + ta * 2048);
      vr0 = *(const int4*)(vp + ta * 64);
      kr1 = *(const int4*)(kp + tb * 2048);
      vr1 = *(const int4*)(vp + tb * 64);
    }
    compute(K0a, V0a);
    compute(K0b, V0b);
    __syncthreads();
    *(int4*)&K0a[kwoff] = kr0;
    *(int4*)&V0a[vwoff] = vr0;
    *(int4*)&K0b[kwoff] = kr1;
    *(int4*)&V0b[vwoff] = vr1;
    {
      const int ta = (4 * i + 6) & 31, tb = (4 * i + 7) & 31;
      kr0 = *(const int4*)(kp + ta * 2048);
      vr0 = *(const int4*)(vp + ta * 64);
      kr1 = *(const int4*)(kp + tb * 2048);
      vr1 = *(const int4*)(vp + tb * 64);
    }
    compute(K1a, V1a);
    compute(K1b, V1b);
    __syncthreads();
  }

  const size_t pbase = (size_t)(sp * 8 + h) * 2048;
  unsigned short* po0 = part_o + (pbase + q0 + c) * 32;
  *(uint2*)&po0[4 * g]      = pack4(acc00);
  *(uint2*)&po0[16 + 4 * g] = pack4(acc01);
  unsigned short* po1 = part_o + (pbase + q0 + 16 + c) * 32;
  *(uint2*)&po1[4 * g]      = pack4(acc10);
  *(uint2*)&po1[16 + 4 * g] = pack4(acc11);
  if (lane < 16) {
    part_l[pbase + q0 + lane]      = accL0[0];
    part_l[pbase + q0 + 16 + lane] = accL1[0];
  }
}

// ---------------------------------------------------------------------------
// Output projection with fused split-combine + normalization + bias.
// Col-split: grid (32,2); 512 thr = 8 waves; 64 rows x 128 cols per block.
// ---------------------------------------------------------------------------
__global__ __launch_bounds__(512) void oproj14_kernel(
    const unsigned short* __restrict__ part_o, const float* __restrict__ part_l,
    const unsigned short* __restrict__ Wt, const float* __restrict__ bias,
    float* __restrict__ out)
{
  const int tid = threadIdx.x;
  const int w = tid >> 6, lane = tid & 63, g = lane >> 4, c = lane & 15;
  const int m0 = blockIdx.x * 64, cb = blockIdx.y * 128;

  __shared__ __align__(16) unsigned short As[64 * 40];
  __shared__ __align__(16) unsigned short Ws[128 * 40];

  const f32x4 zero4 = {0.f, 0.f, 0.f, 0.f};
  f32x4 acc[4];
  #pragma unroll
  for (int i = 0; i < 4; ++i) acc[i] = zero4;

  const int arow = tid >> 3, aseg = (tid & 7) * 4;   // 64 rows x 32 d
  const int wrow = tid >> 2, wseg = (tid & 3) * 8;   // 128 rows x 32 k

  for (int k0 = 0; k0 < 256; k0 += 32) {
    const int h = k0 >> 5;
    if (k0) __syncthreads();
    {
      float L = 0.f;
      float o0 = 0.f, o1 = 0.f, o2 = 0.f, o3 = 0.f;
      #pragma unroll
      for (int s = 0; s < 8; ++s) {
        const size_t b = (size_t)(s * 8 + h) * 2048 + m0 + arow;
        L += part_l[b];
        uint2 pk = *(const uint2*)&part_o[b * 32 + aseg];
        o0 += bf2f(pk.x & 0xffffu); o1 += bf2f(pk.x >> 16);
        o2 += bf2f(pk.y & 0xffffu); o3 += bf2f(pk.y >> 16);
      }
      const float inv = 1.f / L;
      uint2 pa = { pk2(o0 * inv, o1 * inv), pk2(o2 * inv, o3 * inv) };
      *(uint2*)&As[arow * 40 + aseg] = pa;
    }
    {
      const unsigned short* wp = Wt + (size_t)(cb + wrow) * 256 + k0 + wseg;
      int4 w0 = *(const int4*)wp;
      *(int4*)&Ws[wrow * 40 + wseg] = w0;
    }
    __syncthreads();

    bf16x8 a[4];
    #pragma unroll
    for (int rt = 0; rt < 4; ++rt)
      a[rt] = *(const bf16x8*)&As[(16 * rt + c) * 40 + 8 * g];
    bf16x8 b = *(const bf16x8*)&Ws[(16 * w + c) * 40 + 8 * g];
    #pragma unroll
    for (int rt = 0; rt < 4; ++rt)
      acc[rt] = mfma16(a[rt], b, acc[rt]);
  }

  const int col = cb + 16 * w + c;
  const float bv = bias[col];
  #pragma unroll
  for (int rt = 0; rt < 4; ++rt)
    #pragma unroll
    for (int r = 0; r < 4; ++r)
      out[(size_t)(m0 + 16 * rt + 4 * g + r) * 256 + col] = acc[rt][r] + bv;
}

// ---------------------------------------------------------------------------
// Workspace (total 26,869,760 B -- proven-safe):
//   qh     @        0  (1 MB)    bf16 [8][2048][32]
//   khp    @  1048576  (8 MB)    bf16 [8][16384][32]
//   vtp    @  9437184  (8 MB)    bf16 [8][32][16384]  (pi-permuted V^T)
//   part_o @ 17825792  (8 MB)    bf16 [8sp][8h][2048][32]  (unnormalized)
//     wtq/wtk/wtv overlay part_o (dead before attn writes it)
//   part_l @ 26214400  (512 KB)  f32  [8sp][8h][2048]
//   wto    @ 26738688  (128 KB)  bf16 [256][256]
// ---------------------------------------------------------------------------
extern "C" void kernel_launch(void* const* d_in, const int* in_sizes, int n_in,
                              void* d_out, int out_size, void* d_ws, size_t ws_size,
                              hipStream_t stream)
{
  (void)in_sizes; (void)n_in; (void)out_size; (void)ws_size;
  const float* query = (const float*)d_in[0];
  const float* key   = (const float*)d_in[1];
  const float* value = (const float*)d_in[2];
  const float* wq    = (const float*)d_in[3];
  const float* bq    = (const float*)d_in[4];
  const float* wk    = (const float*)d_in[5];
  const float* bk    = (const float*)d_in[6];
  const float* wv    = (const float*)d_in[7];
  const float* bv    = (const float*)d_in[8];
  const float* wo    = (const float*)d_in[9];
  const float* bo    = (const float*)d_in[10];
  float* out = (float*)d_out;

  unsigned char* ws = (unsigned char*)d_ws;
  unsigned short* qh     = (unsigned short*)(ws);
  unsigned short* khp    = (unsigned short*)(ws + 1048576);
  unsigned short* vtp    = (unsigned short*)(ws + 9437184);
  unsigned short* part_o = (unsigned short*)(ws + 17825792);
  unsigned short* wtq    = (unsigned short*)(ws + 17825792);  // overlay part_o
  unsigned short* wtk    = (unsigned short*)(ws + 17956864);
  unsigned short* wtv    = (unsigned short*)(ws + 18087936);
  float*          part_l = (float*)(ws + 26214400);
  unsigned short* wto    = (unsigned short*)(ws + 26738688);

  convert_w_kernel<<<256, 256, 0, stream>>>(wq, wk, wv, wo, wtq, wtk, wtv, wto);
  proj6_kernel<<<dim3(256, 3), 512, 0, stream>>>(
      query, key, value, wtq, wtk, wtv, bq, bk, bv, qh, khp, vtp);
  attn14_kernel<<<dim3(16, 8, 8), 256, 0, stream>>>(qh, khp, vtp, part_o, part_l);
  oproj14_kernel<<<dim3(32, 2), 512, 0, stream>>>(part_o, part_l, wto, bo, out);
}

// Round 15
// 94.720 us; speedup vs baseline: 1.0572x; 1.0572x over previous
//
#include <hip/hip_runtime.h>
#include <stdint.h>

// ---------------------------------------------------------------------------
// Fused MHA v15 == v13 (measured best: 95.9 us; v14's dbuf proj reverted).
//   convert_w -> proj (64-row blocks; V stored pi-permuted V^T) ->
//   flash attn (256-thr/4-wave, 32 q/wave, 128-key phases, explicit dbuf,
//   swapped QK^T, static-max exp2, ones-MFMA row-sums, split-K=8, bf16
//   partials, XCD swizzle, perm P pack, __launch_bounds__(256,4) -> VGPR 60,
//   4 blocks/CU) -> oproj (fused combine+normalize+bias, col-split)
// Proven-regression ledger: proj-128row (v12 +3.6us), proj-dbuf (v14 +4.2us),
// sp=16 (v9 +27us), 128-thr attn blocks (v9), oproj-16row (v5 +17us).
// v_cvt_pk_bf16_f32 BANNED (v8/v10: absmax 3.051758e-3 from P pack alone).
// MFMA v_mfma_f32_16x16x32_bf16 layouts (HW-verified r1/r3):
//   A: row=lane&15, k=8*(lane>>4)+j ; B: col=lane&15, k=8*(lane>>4)+j
//   D: col=lane&15, row=4*(lane>>4)+reg
// P residence after swapped QK^T: lane(g,c) holds P[key][q=c]; as B-operand
// k=8g+j maps to key pi(8g+j) (pi: key bits = k2 k4 k3 k1 k0). V^T is stored
// to global with key-slot sigma(t) = (t&~31) | pi^-1(t&31) so contiguous
// A-fragment reads deliver V[pi(k)][vd] directly.  [proven v3..v6,v11,v13]
// ---------------------------------------------------------------------------

typedef float f32x4 __attribute__((ext_vector_type(4)));
typedef __bf16 bf16x8 __attribute__((ext_vector_type(8)));

extern "C" __device__ float __ocml_native_exp2_f32(float);

__device__ __forceinline__ unsigned short f2bf(float f) {
  unsigned int u = __builtin_bit_cast(unsigned int, f);
  u += 0x7FFFu + ((u >> 16) & 1u);          // RNE
  return (unsigned short)(u >> 16);
}
__device__ __forceinline__ float bf2f(unsigned u) {
  return __builtin_bit_cast(float, u << 16);
}
__device__ __forceinline__ f32x4 mfma16(bf16x8 a, bf16x8 b, f32x4 c) {
  return __builtin_amdgcn_mfma_f32_16x16x32_bf16(a, b, c, 0, 0, 0);
}
__device__ __forceinline__ float ex2(float x) {
#if __has_builtin(__builtin_amdgcn_exp2f)
  return __builtin_amdgcn_exp2f(x);
#else
  return __ocml_native_exp2_f32(x);
#endif
}
// software RNE pair-pack (PROVEN; weights, staging, partials, combine)
__device__ __forceinline__ unsigned pk2(float a, float b) {
  unsigned short ua = __builtin_bit_cast(unsigned short, (__bf16)a);
  unsigned short ub = __builtin_bit_cast(unsigned short, (__bf16)b);
  return (unsigned)ua | ((unsigned)ub << 16);
}
// fast round-half-up pair-pack — IN-LOOP P PACK ONLY (proven v11, 4.88e-4)
__device__ __forceinline__ unsigned pk2p(float a, float b) {
  unsigned au = __builtin_bit_cast(unsigned, a) + 0x8000u;
  unsigned bu = __builtin_bit_cast(unsigned, b) + 0x8000u;
#if __has_builtin(__builtin_amdgcn_perm)
  return __builtin_amdgcn_perm(bu, au, 0x07060302u);
#else
  return (au >> 16) | (bu & 0xffff0000u);
#endif
}
__device__ __forceinline__ uint2 pack4(f32x4 a) {
  uint2 r;
  r.x = pk2(a[0], a[1]);
  r.y = pk2(a[2], a[3]);
  return r;
}

#define QSCALE 0.25503483f  /* log2(e)/sqrt(32) */

// ---------------------------------------------------------------------------
// Convert weights f32 [256k][256n] -> bf16 transposed [256n][256k].
// ---------------------------------------------------------------------------
__global__ __launch_bounds__(256) void convert_w_kernel(
    const float* __restrict__ wq, const float* __restrict__ wk,
    const float* __restrict__ wv, const float* __restrict__ wo,
    unsigned short* __restrict__ tq, unsigned short* __restrict__ tk,
    unsigned short* __restrict__ tv, unsigned short* __restrict__ to)
{
  const int mat = blockIdx.x >> 6, k0 = (blockIdx.x & 63) * 4, n = threadIdx.x;
  const float* src; unsigned short* dst;
  if (mat == 0) { src = wq; dst = tq; }
  else if (mat == 1) { src = wk; dst = tk; }
  else if (mat == 2) { src = wv; dst = tv; }
  else { src = wo; dst = to; }
  float e0 = src[(size_t)(k0 + 0) * 256 + n];
  float e1 = src[(size_t)(k0 + 1) * 256 + n];
  float e2 = src[(size_t)(k0 + 2) * 256 + n];
  float e3 = src[(size_t)(k0 + 3) * 256 + n];
  uint2 pk = { pk2(e0, e1), pk2(e2, e3) };
  *(uint2*)&dst[(size_t)n * 256 + k0] = pk;
}

// ---------------------------------------------------------------------------
// All three projections in one launch (v11/v13-proven). 512 thr = 8 waves;
// 64 rows x 256 cols. blockIdx.y: 0=Q, 1=K, 2=V (pi-permuted V^T store).
// ---------------------------------------------------------------------------
__global__ __launch_bounds__(512) void proj4_kernel(
    const float* __restrict__ Xq, const float* __restrict__ Xk,
    const float* __restrict__ Xv,
    const unsigned short* __restrict__ Wtq, const unsigned short* __restrict__ Wtk,
    const unsigned short* __restrict__ Wtv,
    const float* __restrict__ Bq, const float* __restrict__ Bk,
    const float* __restrict__ Bv,
    unsigned short* __restrict__ Oq, unsigned short* __restrict__ Ok,
    unsigned short* __restrict__ Ov)
{
  const int mat = blockIdx.y;
  const float* X; const unsigned short* Wt; const float* Bp; unsigned short* Op;
  int N; float scale; int vmode;
  if (mat == 0) {
    if (blockIdx.x >= 32) return;
    X = Xq; Wt = Wtq; Bp = Bq; Op = Oq; N = 2048; scale = QSCALE; vmode = 0;
  } else if (mat == 1) {
    X = Xk; Wt = Wtk; Bp = Bk; Op = Ok; N = 16384; scale = 1.f; vmode = 0;
  } else {
    X = Xv; Wt = Wtv; Bp = Bv; Op = Ov; N = 16384; scale = 1.f; vmode = 1;
  }
  const int tid = threadIdx.x;
  const int w = tid >> 6, lane = tid & 63, g = lane >> 4, c = lane & 15;
  const int m0 = blockIdx.x * 64;

  __shared__ __align__(16) unsigned short Xs[64 * 40];
  __shared__ __align__(16) unsigned short Ws[256 * 40];

  const f32x4 zero4 = {0.f, 0.f, 0.f, 0.f};
  f32x4 acc[4][2];
  #pragma unroll
  for (int i = 0; i < 4; ++i) { acc[i][0] = zero4; acc[i][1] = zero4; }

  const int xrow = tid >> 3, xseg = (tid & 7) * 4;   // 64x32 f32 -> 1 float4/thr
  const int wrow = tid >> 1, wseg = (tid & 1) * 16;  // 256x32 bf16 -> 2 int4/thr

  for (int k0 = 0; k0 < 256; k0 += 32) {
    if (k0) __syncthreads();
    {
      float4 x = *(const float4*)&X[(size_t)(m0 + xrow) * 256 + k0 + xseg];
      uint2 px = { pk2(x.x, x.y), pk2(x.z, x.w) };
      *(uint2*)&Xs[xrow * 40 + xseg] = px;
    }
    {
      const unsigned short* wp = Wt + (size_t)wrow * 256 + k0 + wseg;
      int4 w0 = *(const int4*)wp;
      int4 w1 = *(const int4*)(wp + 8);
      *(int4*)&Ws[wrow * 40 + wseg] = w0;
      *(int4*)&Ws[wrow * 40 + wseg + 8] = w1;
    }
    __syncthreads();

    bf16x8 a[4], b[2];
    #pragma unroll
    for (int rt = 0; rt < 4; ++rt)
      a[rt] = *(const bf16x8*)&Xs[(16 * rt + c) * 40 + 8 * g];
    #pragma unroll
    for (int ct = 0; ct < 2; ++ct)
      b[ct] = *(const bf16x8*)&Ws[(32 * w + 16 * ct + c) * 40 + 8 * g];
    #pragma unroll
    for (int rt = 0; rt < 4; ++rt)
      #pragma unroll
      for (int ct = 0; ct < 2; ++ct)
        acc[rt][ct] = mfma16(a[rt], b[ct], acc[rt][ct]);
  }

  #pragma unroll
  for (int ct = 0; ct < 2; ++ct) {
    const int col = 32 * w + 16 * ct + c;
    const float bv = Bp[col];
    const int hh = col >> 5, d = col & 31;
    #pragma unroll
    for (int rt = 0; rt < 4; ++rt)
      #pragma unroll
      for (int r = 0; r < 4; ++r) {
        const int row = m0 + 16 * rt + 4 * g + r;
        const unsigned short v = f2bf((acc[rt][ct][r] + bv) * scale);
        if (vmode) {
          const int pr = (row & ~31) | (((row >> 3) & 1) << 4) |
                         (((row >> 2) & 1) << 3) | (((row >> 4) & 1) << 2) |
                         (row & 3);
          Op[((size_t)hh * 32 + d) * (size_t)N + pr] = v;
        } else {
          Op[((size_t)hh * N + row) * 32 + d] = v;
        }
      }
  }
}

// ---------------------------------------------------------------------------
// Flash attention (v13-proven, unchanged). Grid (16 qb, 8 h, 8 sp),
// XCD-swizzled; 256 thr = 4 waves x 32 q; 16 phases x 128 keys, explicit
// dbuf, ONE barrier per phase; __launch_bounds__(256,4) -> VGPR 60.
// ---------------------------------------------------------------------------
__global__ __launch_bounds__(256, 4) void attn15_kernel(
    const unsigned short* __restrict__ qh, const unsigned short* __restrict__ kh,
    const unsigned short* __restrict__ vth,
    unsigned short* __restrict__ part_o, float* __restrict__ part_l)
{
  const int f = blockIdx.x + 16 * (blockIdx.y + 8 * blockIdx.z);
  const int v = (f & 7) * 128 + (f >> 3);
  const int qb = v & 15, h = (v >> 4) & 7, sp = v >> 7;

  const int tid = threadIdx.x;
  const int w = tid >> 6, lane = tid & 63, g = lane >> 4, c = lane & 15;
  const int q0 = qb * 128 + w * 32;

  __shared__ __align__(16) unsigned short K0a[64 * 40], K0b[64 * 40];
  __shared__ __align__(16) unsigned short K1a[64 * 40], K1b[64 * 40];
  __shared__ __align__(16) unsigned short V0a[32 * 72], V0b[32 * 72];
  __shared__ __align__(16) unsigned short V1a[32 * 72], V1b[32 * 72];

  const bf16x8 qf0 = *(const bf16x8*)&qh[((size_t)h * 2048 + q0 + c) * 32 + 8 * g];
  const bf16x8 qf1 = *(const bf16x8*)&qh[((size_t)h * 2048 + q0 + 16 + c) * 32 + 8 * g];

  bf16x8 ones;
  #pragma unroll
  for (int j = 0; j < 8; ++j) ones[j] = (__bf16)1.0f;

  const f32x4 zero4 = {0.f, 0.f, 0.f, 0.f};
  f32x4 acc00 = zero4, acc01 = zero4, acc10 = zero4, acc11 = zero4;
  f32x4 accL0 = zero4, accL1 = zero4;

  const int skey = tid >> 2, sseg = (tid & 3) * 8;
  const int kwoff = skey * 40 + sseg;
  const int vrow = tid >> 3, vseg = (tid & 7) * 8;
  const int vwoff = vrow * 72 + vseg;

  const unsigned short* kp = kh + (size_t)h * 524288 +
                             ((size_t)(sp * 2048) + skey) * 32 + sseg;
  const unsigned short* vp = vth + ((size_t)h * 32 + vrow) * 16384 +
                             sp * 2048 + vseg;

  auto compute = [&](const unsigned short* Kb, const unsigned short* Vb) {
    bf16x8 kf0 = *(const bf16x8*)&Kb[(c) * 40 + 8 * g];
    bf16x8 kf1 = *(const bf16x8*)&Kb[(16 + c) * 40 + 8 * g];
    bf16x8 kf2 = *(const bf16x8*)&Kb[(32 + c) * 40 + 8 * g];
    bf16x8 kf3 = *(const bf16x8*)&Kb[(48 + c) * 40 + 8 * g];
    f32x4 s0 = mfma16(kf0, qf0, zero4);
    f32x4 s1 = mfma16(kf1, qf0, zero4);
    f32x4 s2 = mfma16(kf2, qf0, zero4);
    f32x4 s3 = mfma16(kf3, qf0, zero4);
    f32x4 t0 = mfma16(kf0, qf1, zero4);
    f32x4 t1 = mfma16(kf1, qf1, zero4);
    f32x4 t2 = mfma16(kf2, qf1, zero4);
    f32x4 t3 = mfma16(kf3, qf1, zero4);

    union { unsigned u[4]; bf16x8 v; } pa00, pa01, pa10, pa11;
    pa00.u[0] = pk2p(ex2(s0[0]), ex2(s0[1]));
    pa00.u[1] = pk2p(ex2(s0[2]), ex2(s0[3]));
    pa00.u[2] = pk2p(ex2(s1[0]), ex2(s1[1]));
    pa00.u[3] = pk2p(ex2(s1[2]), ex2(s1[3]));
    pa01.u[0] = pk2p(ex2(s2[0]), ex2(s2[1]));
    pa01.u[1] = pk2p(ex2(s2[2]), ex2(s2[3]));
    pa01.u[2] = pk2p(ex2(s3[0]), ex2(s3[1]));
    pa01.u[3] = pk2p(ex2(s3[2]), ex2(s3[3]));
    pa10.u[0] = pk2p(ex2(t0[0]), ex2(t0[1]));
    pa10.u[1] = pk2p(ex2(t0[2]), ex2(t0[3]));
    pa10.u[2] = pk2p(ex2(t1[0]), ex2(t1[1]));
    pa10.u[3] = pk2p(ex2(t1[2]), ex2(t1[3]));
    pa11.u[0] = pk2p(ex2(t2[0]), ex2(t2[1]));
    pa11.u[1] = pk2p(ex2(t2[2]), ex2(t2[3]));
    pa11.u[2] = pk2p(ex2(t3[0]), ex2(t3[1]));
    pa11.u[3] = pk2p(ex2(t3[2]), ex2(t3[3]));

    bf16x8 v00 = *(const bf16x8*)&Vb[c * 72 + 8 * g];
    bf16x8 v01 = *(const bf16x8*)&Vb[c * 72 + 32 + 8 * g];
    bf16x8 v10 = *(const bf16x8*)&Vb[(16 + c) * 72 + 8 * g];
    bf16x8 v11 = *(const bf16x8*)&Vb[(16 + c) * 72 + 32 + 8 * g];
    __builtin_amdgcn_s_setprio(1);
    acc00 = mfma16(v00, pa00.v, acc00);
    acc01 = mfma16(v10, pa00.v, acc01);
    accL0 = mfma16(ones, pa00.v, accL0);
    acc00 = mfma16(v01, pa01.v, acc00);
    acc01 = mfma16(v11, pa01.v, acc01);
    accL0 = mfma16(ones, pa01.v, accL0);
    acc10 = mfma16(v00, pa10.v, acc10);
    acc11 = mfma16(v10, pa10.v, acc11);
    accL1 = mfma16(ones, pa10.v, accL1);
    acc10 = mfma16(v01, pa11.v, acc10);
    acc11 = mfma16(v11, pa11.v, acc11);
    accL1 = mfma16(ones, pa11.v, accL1);
    __builtin_amdgcn_s_setprio(0);
  };

  {
    int4 ka = *(const int4*)kp;
    int4 va = *(const int4*)vp;
    int4 kb = *(const int4*)(kp + 2048);
    int4 vb = *(const int4*)(vp + 64);
    *(int4*)&K0a[kwoff] = ka;
    *(int4*)&V0a[vwoff] = va;
    *(int4*)&K0b[kwoff] = kb;
    *(int4*)&V0b[vwoff] = vb;
  }
  int4 kr0 = *(const int4*)(kp + 2 * 2048);
  int4 vr0 = *(const int4*)(vp + 2 * 64);
  int4 kr1 = *(const int4*)(kp + 3 * 2048);
  int4 vr1 = *(const int4*)(vp + 3 * 64);
  __syncthreads();

  for (int i = 0; i < 8; ++i) {
    *(int4*)&K1a[kwoff] = kr0;
    *(int4*)&V1a[vwoff] = vr0;
    *(int4*)&K1b[kwoff] = kr1;
    *(int4*)&V1b[vwoff] = vr1;
    {
      const int ta = (4 * i + 4) & 31, tb = (4 * i + 5) & 31;
      kr0 = *(const int4*)(kp + ta * 2048);
      vr0 = *(const int4*)(vp + ta * 64);
      kr1 = *(const int4*)(kp + tb * 2048);
      vr1 = *(const int4*)(vp + tb * 64);
    }
    compute(K0a, V0a);
    compute(K0b, V0b);
    __syncthreads();
    *(int4*)&K0a[kwoff] = kr0;
    *(int4*)&V0a[vwoff] = vr0;
    *(int4*)&K0b[kwoff] = kr1;
    *(int4*)&V0b[vwoff] = vr1;
    {
      const int ta = (4 * i + 6) & 31, tb = (4 * i + 7) & 31;
      kr0 = *(const int4*)(kp + ta * 2048);
      vr0 = *(const int4*)(vp + ta * 64);
      kr1 = *(const int4*)(kp + tb * 2048);
      vr1 = *(const int4*)(vp + tb * 64);
    }
    compute(K1a, V1a);
    compute(K1b, V1b);
    __syncthreads();
  }

  const size_t pbase = (size_t)(sp * 8 + h) * 2048;
  unsigned short* po0 = part_o + (pbase + q0 + c) * 32;
  *(uint2*)&po0[4 * g]      = pack4(acc00);
  *(uint2*)&po0[16 + 4 * g] = pack4(acc01);
  unsigned short* po1 = part_o + (pbase + q0 + 16 + c) * 32;
  *(uint2*)&po1[4 * g]      = pack4(acc10);
  *(uint2*)&po1[16 + 4 * g] = pack4(acc11);
  if (lane < 16) {
    part_l[pbase + q0 + lane]      = accL0[0];
    part_l[pbase + q0 + 16 + lane] = accL1[0];
  }
}

// ---------------------------------------------------------------------------
// Output projection with fused split-combine + normalization + bias.
// Col-split: grid (32,2); 512 thr = 8 waves; 64 rows x 128 cols per block.
// ---------------------------------------------------------------------------
__global__ __launch_bounds__(512) void oproj15_kernel(
    const unsigned short* __restrict__ part_o, const float* __restrict__ part_l,
    const unsigned short* __restrict__ Wt, const float* __restrict__ bias,
    float* __restrict__ out)
{
  const int tid = threadIdx.x;
  const int w = tid >> 6, lane = tid & 63, g = lane >> 4, c = lane & 15;
  const int m0 = blockIdx.x * 64, cb = blockIdx.y * 128;

  __shared__ __align__(16) unsigned short As[64 * 40];
  __shared__ __align__(16) unsigned short Ws[128 * 40];

  const f32x4 zero4 = {0.f, 0.f, 0.f, 0.f};
  f32x4 acc[4];
  #pragma unroll
  for (int i = 0; i < 4; ++i) acc[i] = zero4;

  const int arow = tid >> 3, aseg = (tid & 7) * 4;   // 64 rows x 32 d
  const int wrow = tid >> 2, wseg = (tid & 3) * 8;   // 128 rows x 32 k

  for (int k0 = 0; k0 < 256; k0 += 32) {
    const int h = k0 >> 5;
    if (k0) __syncthreads();
    {
      float L = 0.f;
      float o0 = 0.f, o1 = 0.f, o2 = 0.f, o3 = 0.f;
      #pragma unroll
      for (int s = 0; s < 8; ++s) {
        const size_t b = (size_t)(s * 8 + h) * 2048 + m0 + arow;
        L += part_l[b];
        uint2 pk = *(const uint2*)&part_o[b * 32 + aseg];
        o0 += bf2f(pk.x & 0xffffu); o1 += bf2f(pk.x >> 16);
        o2 += bf2f(pk.y & 0xffffu); o3 += bf2f(pk.y >> 16);
      }
      const float inv = 1.f / L;
      uint2 pa = { pk2(o0 * inv, o1 * inv), pk2(o2 * inv, o3 * inv) };
      *(uint2*)&As[arow * 40 + aseg] = pa;
    }
    {
      const unsigned short* wp = Wt + (size_t)(cb + wrow) * 256 + k0 + wseg;
      int4 w0 = *(const int4*)wp;
      *(int4*)&Ws[wrow * 40 + wseg] = w0;
    }
    __syncthreads();

    bf16x8 a[4];
    #pragma unroll
    for (int rt = 0; rt < 4; ++rt)
      a[rt] = *(const bf16x8*)&As[(16 * rt + c) * 40 + 8 * g];
    bf16x8 b = *(const bf16x8*)&Ws[(16 * w + c) * 40 + 8 * g];
    #pragma unroll
    for (int rt = 0; rt < 4; ++rt)
      acc[rt] = mfma16(a[rt], b, acc[rt]);
  }

  const int col = cb + 16 * w + c;
  const float bv = bias[col];
  #pragma unroll
  for (int rt = 0; rt < 4; ++rt)
    #pragma unroll
    for (int r = 0; r < 4; ++r)
      out[(size_t)(m0 + 16 * rt + 4 * g + r) * 256 + col] = acc[rt][r] + bv;
}

// ---------------------------------------------------------------------------
// Workspace (total 26,869,760 B -- proven-safe):
//   qh     @        0  (1 MB)    bf16 [8][2048][32]
//   khp    @  1048576  (8 MB)    bf16 [8][16384][32]
//   vtp    @  9437184  (8 MB)    bf16 [8][32][16384]  (pi-permuted V^T)
//   part_o @ 17825792  (8 MB)    bf16 [8sp][8h][2048][32]  (unnormalized)
//     wtq/wtk/wtv overlay part_o (dead before attn writes it)
//   part_l @ 26214400  (512 KB)  f32  [8sp][8h][2048]
//   wto    @ 26738688  (128 KB)  bf16 [256][256]
// ---------------------------------------------------------------------------
extern "C" void kernel_launch(void* const* d_in, const int* in_sizes, int n_in,
                              void* d_out, int out_size, void* d_ws, size_t ws_size,
                              hipStream_t stream)
{
  (void)in_sizes; (void)n_in; (void)out_size; (void)ws_size;
  const float* query = (const float*)d_in[0];
  const float* key   = (const float*)d_in[1];
  const float* value = (const float*)d_in[2];
  const float* wq    = (const float*)d_in[3];
  const float* bq    = (const float*)d_in[4];
  const float* wk    = (const float*)d_in[5];
  const float* bk    = (const float*)d_in[6];
  const float* wv    = (const float*)d_in[7];
  const float* bv    = (const float*)d_in[8];
  const float* wo    = (const float*)d_in[9];
  const float* bo    = (const float*)d_in[10];
  float* out = (float*)d_out;

  unsigned char* ws = (unsigned char*)d_ws;
  unsigned short* qh     = (unsigned short*)(ws);
  unsigned short* khp    = (unsigned short*)(ws + 1048576);
  unsigned short* vtp    = (unsigned short*)(ws + 9437184);
  unsigned short* part_o = (unsigned short*)(ws + 17825792);
  unsigned short* wtq    = (unsigned short*)(ws + 17825792);  // overlay part_o
  unsigned short* wtk    = (unsigned short*)(ws + 17956864);
  unsigned short* wtv    = (unsigned short*)(ws + 18087936);
  float*          part_l = (float*)(ws + 26214400);
  unsigned short* wto    = (unsigned short*)(ws + 26738688);

  convert_w_kernel<<<256, 256, 0, stream>>>(wq, wk, wv, wo, wtq, wtk, wtv, wto);
  proj4_kernel<<<dim3(256, 3), 512, 0, stream>>>(
      query, key, value, wtq, wtk, wtv, bq, bk, bv, qh, khp, vtp);
  attn15_kernel<<<dim3(16, 8, 8), 256, 0, stream>>>(qh, khp, vtp, part_o, part_l);
  oproj15_kernel<<<dim3(32, 2), 512, 0, stream>>>(part_o, part_l, wto, bo, out);
}